// Round 5
// baseline (209.312 us; speedup 1.0000x reference)
//
#include <hip/hip_runtime.h>
#include <cfloat>
#include <cmath>

#define NB 2048
#define BB 16
#define DD 128
#define HH 64
#define MAXC 5
#define CSMAX 3
#define NT 1024

// ---------------- Threefry-2x32 (JAX-exact) ----------------
__device__ __forceinline__ unsigned rotl32(unsigned v, int d) {
  return (v << d) | (v >> (32 - d));
}

__device__ __forceinline__ void tf2x32(unsigned k0, unsigned k1, unsigned x0, unsigned x1,
                                       unsigned& o0, unsigned& o1) {
  unsigned ks2 = k0 ^ k1 ^ 0x1BD11BDAu;
  x0 += k0; x1 += k1;
#define RND(r) { x0 += x1; x1 = rotl32(x1, r); x1 ^= x0; }
  RND(13) RND(15) RND(26) RND(6)   x0 += k1;  x1 += ks2 + 1u;
  RND(17) RND(29) RND(16) RND(24)  x0 += ks2; x1 += k0 + 2u;
  RND(13) RND(15) RND(26) RND(6)   x0 += k0;  x1 += k1 + 3u;
  RND(17) RND(29) RND(16) RND(24)  x0 += k1;  x1 += ks2 + 4u;
  RND(13) RND(15) RND(26) RND(6)   x0 += ks2; x1 += k0 + 5u;
#undef RND
  o0 = x0; o1 = x1;
}

__device__ __forceinline__ float gumbel_for(unsigned k0, unsigned k1, unsigned idx) {
  unsigned o0, o1;
  tf2x32(k0, k1, 0u, idx, o0, o1);
  unsigned bits = o0 ^ o1;
  float u = __uint_as_float((bits >> 9) | 0x3f800000u) - 1.0f;
  float uu = u + 1e-8f;
  return -logf(-logf(uu) + 1e-8f);
}

// ---------------- Fused prep: P-GEMM tiles + mean partials + gumbel ----------------
__global__ __launch_bounds__(NT) void gvp_prep(
    const float* __restrict__ x, const float* __restrict__ W1,
    float* __restrict__ P, float* __restrict__ partial, float* __restrict__ gumb) {
  __shared__ __align__(16) float s_W1[HH][DD + 4];
  __shared__ float sp[8][DD];
  const int bid = blockIdx.x, tid = threadIdx.x;

  if (bid < 128) {
    for (int i = tid; i < HH * (DD / 4); i += NT) {
      int r = i >> 5, q = i & 31;
      *(float4*)&s_W1[r][q * 4] = *(const float4*)(W1 + (size_t)r * (DD + HH) + q * 4);
    }
    __syncthreads();
    const int jg = tid & 15, ng = tid >> 4;
    const int j0 = jg * 4;
    const size_t n0 = (size_t)bid * 256 + ng * 4;
    const float4* x4 = (const float4*)x;
    float acc[4][4];
#pragma unroll
    for (int i = 0; i < 4; i++)
#pragma unroll
      for (int q = 0; q < 4; q++) acc[i][q] = 0.f;
    for (int kq = 0; kq < 32; kq++) {
      float4 xv[4], wv[4];
#pragma unroll
      for (int i = 0; i < 4; i++) xv[i] = x4[(n0 + i) * 32 + kq];
#pragma unroll
      for (int q = 0; q < 4; q++) wv[q] = *(const float4*)&s_W1[j0 + q][kq * 4];
#pragma unroll
      for (int i = 0; i < 4; i++)
#pragma unroll
        for (int q = 0; q < 4; q++)
          acc[i][q] += xv[i].x * wv[q].x + xv[i].y * wv[q].y +
                       xv[i].z * wv[q].z + xv[i].w * wv[q].w;
    }
#pragma unroll
    for (int i = 0; i < 4; i++)
#pragma unroll
      for (int q = 0; q < 4; q++)
        P[(n0 + i) * HH + j0 + q] = acc[i][q];
  } else if (bid < 384) {
    const int bm = bid - 128;
    const int b = bm >> 4, chunk = bm & 15;
    const int d = tid & (DD - 1), part = tid >> 7;
    float acc = 0.f;
    const int base = chunk * 128 + part;
#pragma unroll
    for (int k = 0; k < 16; k++)
      acc += x[((size_t)b * NB + base + k * 8) * DD + d];
    sp[part][d] = acc;
    __syncthreads();
    if (tid < DD) {
      float m = 0.f;
#pragma unroll
      for (int p = 0; p < 8; p++) m += sp[p][tid];
      partial[((size_t)b * 16 + chunk) * DD + tid] = m;
    }
  } else {
    const int bg = bid - 384;
    const int base = (bg * NT + tid) * 4;
#pragma unroll
    for (int i = 0; i < 4; i++) {
      int idx = base + i;
      int sel = idx >> 15;
      int rem = idx & 32767;
      int c = sel / 3, s = sel - 3 * c;
      unsigned data = (s == 0) ? (unsigned)(2 * c) : (unsigned)(2 * c + 1000 + (s - 1));
      unsigned k0, k1;
      tf2x32(0u, 42u, 0u, data, k0, k1);
      gumb[idx] = gumbel_for(k0, k1, (unsigned)rem);
    }
  }
}

// ---------------- Main: one block (1024 thr) per batch ----------------
__global__ __launch_bounds__(NT, 4) void gvp_main(
    const float* __restrict__ x, const float* __restrict__ adj, const int* __restrict__ mask,
    const float* __restrict__ W1, const float* __restrict__ b1,
    const float* __restrict__ W2, const float* __restrict__ b2,
    const float* __restrict__ Wc, const float* __restrict__ bc,
    const float* __restrict__ Wih, const float* __restrict__ Whh,
    const float* __restrict__ bih, const float* __restrict__ bhh,
    const float* __restrict__ P, const float* __restrict__ partial,
    const float* __restrict__ gumb,
    float* __restrict__ out_feat, float* __restrict__ out_adjm, float* __restrict__ out_assign) {
  const int b = blockIdx.x;
  const int tid = threadIdx.x;

  __shared__ __align__(16) float s_logits[NB];
  __shared__ __align__(16) float s_gumb[2][NB];
  __shared__ unsigned char s_avail[NB], s_reach[NB], s_assignB[NB];
  __shared__ short s_list[128];
  __shared__ int s_cnt;
  __shared__ unsigned long long s_key[CSMAX];
  __shared__ __align__(16) float s_ctx[HH], s_q[HH];
  __shared__ __align__(16) float s_h[2][HH];
  __shared__ __align__(16) float s_hist[MAXC][DD];
  __shared__ __align__(16) float s_giAll[MAXC][3 * HH];
  __shared__ __align__(16) float s_Whh[3 * HH][HH + 4];
  __shared__ __align__(16) float s_W1c[HH][HH + 4];
  __shared__ __align__(16) float s_W2[HH];
  __shared__ float s_bhh[3 * HH], s_b1[HH];
  __shared__ __align__(16) float s_mean[DD];
  __shared__ float s_b2v;

  const size_t xb = (size_t)b * NB * DD;
  const float4* adj4 = (const float4*)(adj + (size_t)b * NB * NB);
  const float4* P4 = (const float4*)(P + (size_t)b * NB * HH);
  const int n0 = tid, n1 = tid + NT;

  auto scanReduce = [&](float bv, int bi, int slot) {
#pragma unroll
    for (int off = 32; off; off >>= 1) {
      float ov = __shfl_down(bv, off);
      int oi = __shfl_down(bi, off);
      if (ov > bv || (ov == bv && oi < bi)) { bv = ov; bi = oi; }
    }
    if ((tid & 63) == 0 && bi < NB) {
      unsigned u = __float_as_uint(bv);
      u = (u & 0x80000000u) ? ~u : (u | 0x80000000u);
      unsigned long long key = ((unsigned long long)u << 32) | (unsigned)(~bi);
      atomicMax(&s_key[slot], key);
    }
  };
  auto decodeIdx = [](unsigned long long k) -> int {
    return k ? (int)(unsigned)(~(unsigned)k) : -1;
  };

  // ---- one-time staging ----
  float4 pP[16];  // persistent P row for node n0 (64 VGPR)
  {
    const float4* pr0 = P4 + (size_t)n0 * 16;
#pragma unroll
    for (int i = 0; i < 16; i++) pP[i] = pr0[i];
  }
  for (int i = tid; i < 3 * HH * (HH / 4); i += NT) {
    int r = i >> 4, q = i & 15;
    *(float4*)&s_Whh[r][q * 4] = *(const float4*)(Whh + (size_t)r * HH + q * 4);
  }
  {
    int r = tid >> 4, q = tid & 15;
    *(float4*)&s_W1c[r][q * 4] = *(const float4*)(W1 + (size_t)r * (DD + HH) + DD + q * 4);
  }
  if (tid < 3 * HH) s_bhh[tid] = bhh[tid];
  if (tid < HH) { s_W2[tid] = W2[tid]; s_b1[tid] = b1[tid]; s_h[0][tid] = 0.f; }
  if (tid == 0) s_b2v = b2[0];
#pragma unroll
  for (int r = 0; r < 2; r++) {
    int n = tid + r * NT;
    s_avail[n] = (mask[b * NB + n] != 0) ? 1 : 0;
    s_assignB[n] = 0;
  }
  if (tid < DD) {
    float m = 0.f;
#pragma unroll
    for (int k = 0; k < 16; k++) m += partial[((size_t)b * 16 + k) * DD + tid];
    s_mean[tid] = m * (1.0f / NB);
  }
  // prefetch cluster-0 gumbel into regs
  float4 gst;
  float g0a, g0b;
  {
    const float* g0p = gumb + ((size_t)0 * BB + b) * NB;
    g0a = g0p[n0]; g0b = g0p[n1];
    const float4* g12 = (const float4*)(gumb + ((size_t)(1 + (tid >> 9)) * BB + b) * NB);
    gst = g12[tid & 511];
  }
  __syncthreads();
  if (tid < 4 * HH) {  // ctx = bc + Wc @ mean
    int row = tid >> 2, g = tid & 3;
    const float4* wr = (const float4*)(Wc + (size_t)row * DD) + g * 8;
    const float4* m4 = (const float4*)s_mean + g * 8;
    float s = 0.f;
#pragma unroll
    for (int i = 0; i < 8; i++) {
      float4 w = wr[i], m = m4[i];
      s += w.x * m.x + w.y * m.y + w.z * m.z + w.w * m.w;
    }
    s += __shfl_xor(s, 1);
    s += __shfl_xor(s, 2);
    if (g == 0) s_ctx[row] = s + bc[row];
  }
  __syncthreads();

  int hp = 0;  // GRU h parity (uniform)

  // GRU step executed by threads [lo, lo+256)
  auto gruStep = [&](int t, int lo, int c) {
    int tt = tid - lo;
    if ((unsigned)tt < 256u) {
      int row = tt >> 2, g = tt & 3;
      const float4* h4 = (const float4*)s_h[hp] + g * 4;
      float4 hv[4];
#pragma unroll
      for (int i = 0; i < 4; i++) hv[i] = h4[i];
      const float4* wr = (const float4*)&s_Whh[row][0] + g * 4;
      const float4* wz = (const float4*)&s_Whh[HH + row][0] + g * 4;
      const float4* wn = (const float4*)&s_Whh[2 * HH + row][0] + g * 4;
      float sr = 0.f, sz = 0.f, sn = 0.f;
#pragma unroll
      for (int i = 0; i < 4; i++) {
        float4 a = wr[i], bz = wz[i], cn = wn[i], h = hv[i];
        sr += a.x * h.x + a.y * h.y + a.z * h.z + a.w * h.w;
        sz += bz.x * h.x + bz.y * h.y + bz.z * h.z + bz.w * h.w;
        sn += cn.x * h.x + cn.y * h.y + cn.z * h.z + cn.w * h.w;
      }
      sr += __shfl_xor(sr, 1); sr += __shfl_xor(sr, 2);
      sz += __shfl_xor(sz, 1); sz += __shfl_xor(sz, 2);
      sn += __shfl_xor(sn, 1); sn += __shfl_xor(sn, 2);
      if (g == 0) {
        float r = 1.f / (1.f + expf(-(s_giAll[t][row] + sr + s_bhh[row])));
        float z = 1.f / (1.f + expf(-(s_giAll[t][HH + row] + sz + s_bhh[HH + row])));
        float nn = tanhf(s_giAll[t][2 * HH + row] + r * (sn + s_bhh[2 * HH + row]));
        float hn = (1.f - z) * nn + z * s_h[hp][row];
        s_h[hp ^ 1][row] = hn;
        if (t == c) s_ctx[row] = hn;
      }
    }
  };

  for (int c = 0; c < MAXC; c++) {
    // ======== T: commit prefetched gumbel, q matvec, reset ========
    ((float4*)s_gumb)[tid] = gst;
    if (tid < 4 * HH) {  // q = b1 + W1[:,DD:] @ ctx
      int row = tid >> 2, g = tid & 3;
      const float4* wr = (const float4*)&s_W1c[row][0] + g * 4;
      const float4* c4 = (const float4*)s_ctx + g * 4;
      float s = 0.f;
#pragma unroll
      for (int i = 0; i < 4; i++) {
        float4 w = wr[i], cc = c4[i];
        s += w.x * cc.x + w.y * cc.y + w.z * cc.z + w.w * cc.w;
      }
      s += __shfl_xor(s, 1);
      s += __shfl_xor(s, 2);
      if (g == 0) s_q[row] = s + s_b1[row];
    }
    if (tid >= 512 && tid < 512 + CSMAX) s_key[tid - 512] = 0ull;
    if (tid == 768) s_cnt = 0;
    __syncthreads();

    // ======== L: logits (n0 from regs, n1 streamed) + SEL0 ========
    {
      const float4* p1 = P4 + (size_t)n1 * 16;
      const float4* q4 = (const float4*)s_q;
      const float4* w4 = (const float4*)s_W2;
      float4 Pa[8];
#pragma unroll
      for (int i = 0; i < 8; i++) Pa[i] = p1[i];     // stream chunk 1 (in flight)
      float l0 = s_b2v, l1 = s_b2v;
#pragma unroll
      for (int i = 0; i < 16; i++) {                  // n0 from persistent regs
        float4 p = pP[i], qv = q4[i], w = w4[i];
        l0 += w.x * fmaxf(p.x + qv.x, 0.f) + w.y * fmaxf(p.y + qv.y, 0.f) +
              w.z * fmaxf(p.z + qv.z, 0.f) + w.w * fmaxf(p.w + qv.w, 0.f);
      }
#pragma unroll
      for (int i = 0; i < 8; i++) {                   // consume chunk 1
        float4 p = Pa[i], qv = q4[i], w = w4[i];
        l1 += w.x * fmaxf(p.x + qv.x, 0.f) + w.y * fmaxf(p.y + qv.y, 0.f) +
              w.z * fmaxf(p.z + qv.z, 0.f) + w.w * fmaxf(p.w + qv.w, 0.f);
      }
#pragma unroll
      for (int i = 0; i < 8; i++) Pa[i] = p1[8 + i];  // stream chunk 2
#pragma unroll
      for (int i = 0; i < 8; i++) {
        float4 p = Pa[i], qv = q4[8 + i], w = w4[8 + i];
        l1 += w.x * fmaxf(p.x + qv.x, 0.f) + w.y * fmaxf(p.y + qv.y, 0.f) +
              w.z * fmaxf(p.z + qv.z, 0.f) + w.w * fmaxf(p.w + qv.w, 0.f);
      }
      s_logits[n0] = l0;
      s_logits[n1] = l1;
      float bv = -FLT_MAX;
      int bi = NB;
      if (s_avail[n0]) { float y = l0 + g0a; if (y > bv) { bv = y; bi = n0; } }
      if (s_avail[n1]) { float y = l1 + g0b; if (y > bv || (y == bv && n1 < bi)) { bv = y; bi = n1; } }
      scanReduce(bv, bi, 0);
    }
    __syncthreads();

    // ======== H0: seed row -> reach + frontier ========
    const int seed = decodeIdx(s_key[0]);
    if (tid < 512) {
      if (seed >= 0) {
        float4 a = adj4[(size_t)seed * 512 + tid];
        int m = tid << 2;
        unsigned f0 = a.x > 0.f, f1 = a.y > 0.f, f2 = a.z > 0.f, f3 = a.w > 0.f;
        unsigned r = f0 | (f1 << 8) | (f2 << 16) | (f3 << 24);
        if ((seed >> 2) == tid) r |= 1u << ((seed & 3) * 8);
        ((unsigned*)s_reach)[tid] = r;
        if (f0 && m != seed)     { int p = atomicAdd(&s_cnt, 1); if (p < 128) s_list[p] = (short)m; }
        if (f1 && m + 1 != seed) { int p = atomicAdd(&s_cnt, 1); if (p < 128) s_list[p] = (short)(m + 1); }
        if (f2 && m + 2 != seed) { int p = atomicAdd(&s_cnt, 1); if (p < 128) s_list[p] = (short)(m + 2); }
        if (f3 && m + 3 != seed) { int p = atomicAdd(&s_cnt, 1); if (p < 128) s_list[p] = (short)(m + 3); }
      } else {
        ((unsigned*)s_reach)[tid] = 0u;
      }
    }
    __syncthreads();

    // ======== H1: OR frontier rows into reach ========
    if (seed >= 0) {
      int cnt = min(s_cnt, 128);
      int m4 = tid & 511, rg = tid >> 9;
      bool a0 = false, a1 = false, a2 = false, a3 = false;
#pragma unroll
      for (int k = 0; k < 20; k++) {
        int li = rg + 2 * k;
        if (li < cnt) {
          int n = s_list[li];
          float4 a = adj4[(size_t)n * 512 + m4];
          a0 |= a.x > 0.f; a1 |= a.y > 0.f; a2 |= a.z > 0.f; a3 |= a.w > 0.f;
        }
      }
      for (int li = rg + 40; li < cnt; li += 2) {
        int n = s_list[li];
        float4 a = adj4[(size_t)n * 512 + m4];
        a0 |= a.x > 0.f; a1 |= a.y > 0.f; a2 |= a.z > 0.f; a3 |= a.w > 0.f;
      }
      int m = m4 << 2;
      if (a0) s_reach[m] = 1;
      if (a1) s_reach[m + 1] = 1;
      if (a2) s_reach[m + 2] = 1;
      if (a3) s_reach[m + 3] = 1;
    }
    __syncthreads();

    // ======== S1 ========
    {
      float bv = -FLT_MAX;
      int bi = NB;
#pragma unroll
      for (int r = 0; r < 2; r++) {
        int n = tid + r * NT;
        if (s_avail[n] && s_reach[n] && n != seed) {
          float y = s_logits[n] + s_gumb[0][n];
          if (y > bv || (y == bv && n < bi)) { bv = y; bi = n; }
        }
      }
      scanReduce(bv, bi, 1);
    }
    __syncthreads();

    // ======== S2 ========
    const int w1i = decodeIdx(s_key[1]);
    {
      float bv = -FLT_MAX;
      int bi = NB;
#pragma unroll
      for (int r = 0; r < 2; r++) {
        int n = tid + r * NT;
        if (s_avail[n] && s_reach[n] && n != seed && n != w1i) {
          float y = s_logits[n] + s_gumb[1][n];
          if (y > bv || (y == bv && n < bi)) { bv = y; bi = n; }
        }
      }
      scanReduce(bv, bi, 2);
    }
    __syncthreads();

    // ======== E: prefetch(c+1) + emb || GRU-step0 (c>=1) || avail update ========
    const int w2i = decodeIdx(s_key[2]);
    if (c + 1 < MAXC) {  // prefetch next cluster's gumbel into regs (all threads)
      const float* g0p = gumb + ((size_t)((c + 1) * 3) * BB + b) * NB;
      g0a = g0p[n0]; g0b = g0p[n1];
      const float4* g12 =
          (const float4*)(gumb + ((size_t)((c + 1) * 3 + 1 + (tid >> 9)) * BB + b) * NB);
      gst = g12[tid & 511];
    }
    {
      int mc = (seed >= 0) + (w1i >= 0) + (w2i >= 0);
      if (tid < DD) {
        float acc = 0.f;
        if (seed >= 0) acc += x[xb + (size_t)seed * DD + tid];
        if (w1i >= 0) acc += x[xb + (size_t)w1i * DD + tid];
        if (w2i >= 0) acc += x[xb + (size_t)w2i * DD + tid];
        float e = acc / fmaxf((float)mc, 1.0f);
        s_hist[c][tid] = e;
        out_feat[((size_t)b * MAXC + c) * DD + tid] = e;
      } else if (tid >= 512 && tid < 512 + CSMAX) {
        int idx = (tid == 512) ? seed : (tid == 513 ? w1i : w2i);
        if (idx >= 0) { s_avail[idx] = 0; s_assignB[idx] |= (unsigned char)(1 << c); }
      }
      if (c >= 1) gruStep(0, 256, c);
    }
    __syncthreads();
    if (c >= 1) hp ^= 1;

    // ======== G: gi[c] (tid<768) || GRU-step1 (c>=2, tid in [768,1024)) ========
    if (tid < 4 * 3 * HH) {
      int row = tid >> 2, g = tid & 3;
      const float4* wr = (const float4*)(Wih + (size_t)row * DD) + g * 8;
      const float4* h4 = (const float4*)s_hist[c] + g * 8;
      float s = 0.f;
#pragma unroll
      for (int i = 0; i < 8; i++) {
        float4 w = wr[i], hh = h4[i];
        s += w.x * hh.x + w.y * hh.y + w.z * hh.z + w.w * hh.w;
      }
      s += __shfl_xor(s, 1);
      s += __shfl_xor(s, 2);
      if (g == 0) s_giAll[c][row] = s + bih[row];
    }
    if (c >= 2) gruStep(1, 768, c);
    __syncthreads();
    if (c >= 2) hp ^= 1;

    // ======== R: remaining GRU steps ========
    int t0 = (c == 0) ? 0 : (c == 1) ? 1 : 2;
    for (int t = t0; t <= c; t++) {
      gruStep(t, 0, c);
      hp ^= 1;
      __syncthreads();
    }
  }  // clusters

  // ======== final coalesced assign + cluster_adj ========
#pragma unroll
  for (int r = 0; r < 2; r++) {
    int n = tid + r * NT;
    unsigned bits = s_assignB[n];
    size_t base = ((size_t)(b * NB + n)) * MAXC;
#pragma unroll
    for (int cc = 0; cc < MAXC; cc++)
      out_assign[base + cc] = (float)((bits >> cc) & 1u);
  }
  for (int i = tid; i < MAXC * MAXC; i += NT)
    out_adjm[(size_t)b * MAXC * MAXC + i] = ((i / MAXC) == (i % MAXC)) ? 0.f : 1.f;
}

extern "C" void kernel_launch(void* const* d_in, const int* in_sizes, int n_in,
                              void* d_out, int out_size, void* d_ws, size_t ws_size,
                              hipStream_t stream) {
  const float* x   = (const float*)d_in[0];
  const float* adj = (const float*)d_in[1];
  const int*   mask= (const int*)d_in[2];
  const float* W1  = (const float*)d_in[3];
  const float* b1  = (const float*)d_in[4];
  const float* W2  = (const float*)d_in[5];
  const float* b2  = (const float*)d_in[6];
  const float* Wc  = (const float*)d_in[7];
  const float* bc  = (const float*)d_in[8];
  const float* Wih = (const float*)d_in[9];
  const float* Whh = (const float*)d_in[10];
  const float* bih = (const float*)d_in[11];
  const float* bhh = (const float*)d_in[12];

  float* ws = (float*)d_ws;
  float* P       = ws;                                   // [B*N*HH]  8 MB
  float* partial = P + (size_t)BB * NB * HH;             // [B][16][DD]
  float* gumb    = partial + (size_t)BB * 16 * DD;       // [15][B][N]

  float* out = (float*)d_out;
  float* out_feat = out;                                     // [B,5,D]
  float* out_adjm = out + (size_t)BB * MAXC * DD;            // [B,5,5]
  float* out_assign = out_adjm + (size_t)BB * MAXC * MAXC;   // [B,N,5]

  hipLaunchKernelGGL(gvp_prep, dim3(504), dim3(NT), 0, stream, x, W1, P, partial, gumb);
  hipLaunchKernelGGL(gvp_main, dim3(BB), dim3(NT), 0, stream,
                     x, adj, mask, W1, b1, W2, b2, Wc, bc, Wih, Whh, bih, bhh, P, partial, gumb,
                     out_feat, out_adjm, out_assign);
}

// Round 6
// 201.915 us; speedup vs baseline: 1.0366x; 1.0366x over previous
//
#include <hip/hip_runtime.h>
#include <cfloat>
#include <cmath>

#define NB 2048
#define BB 16
#define DD 128
#define HH 64
#define MAXC 5
#define CSMAX 3
#define NT 1024

// ---------------- Threefry-2x32 (JAX-exact) ----------------
__device__ __forceinline__ unsigned rotl32(unsigned v, int d) {
  return (v << d) | (v >> (32 - d));
}

__device__ __forceinline__ void tf2x32(unsigned k0, unsigned k1, unsigned x0, unsigned x1,
                                       unsigned& o0, unsigned& o1) {
  unsigned ks2 = k0 ^ k1 ^ 0x1BD11BDAu;
  x0 += k0; x1 += k1;
#define RND(r) { x0 += x1; x1 = rotl32(x1, r); x1 ^= x0; }
  RND(13) RND(15) RND(26) RND(6)   x0 += k1;  x1 += ks2 + 1u;
  RND(17) RND(29) RND(16) RND(24)  x0 += ks2; x1 += k0 + 2u;
  RND(13) RND(15) RND(26) RND(6)   x0 += k0;  x1 += k1 + 3u;
  RND(17) RND(29) RND(16) RND(24)  x0 += k1;  x1 += ks2 + 4u;
  RND(13) RND(15) RND(26) RND(6)   x0 += ks2; x1 += k0 + 5u;
#undef RND
  o0 = x0; o1 = x1;
}

__device__ __forceinline__ float gumbel_for(unsigned k0, unsigned k1, unsigned idx) {
  unsigned o0, o1;
  tf2x32(k0, k1, 0u, idx, o0, o1);
  unsigned bits = o0 ^ o1;
  float u = __uint_as_float((bits >> 9) | 0x3f800000u) - 1.0f;
  float uu = u + 1e-8f;
  return -logf(-logf(uu) + 1e-8f);
}

// Raw phase barrier: drain LDS ops only; vmem loads stay in flight across it.
__device__ __forceinline__ void phase_barrier() {
  asm volatile("s_waitcnt lgkmcnt(0)" ::: "memory");
  __builtin_amdgcn_s_barrier();
  asm volatile("" ::: "memory");
}

#define REP16(M) M(0) M(1) M(2) M(3) M(4) M(5) M(6) M(7) \
                 M(8) M(9) M(10) M(11) M(12) M(13) M(14) M(15)
#define REP8(M) M(0) M(1) M(2) M(3) M(4) M(5) M(6) M(7)

// ---------------- Fused prep: P-GEMM tiles + mean partials + gumbel ----------------
__global__ __launch_bounds__(NT) void gvp_prep(
    const float* __restrict__ x, const float* __restrict__ W1,
    float* __restrict__ P, float* __restrict__ partial, float* __restrict__ gumb) {
  __shared__ __align__(16) float s_W1[HH][DD + 4];
  __shared__ float sp[8][DD];
  const int bid = blockIdx.x, tid = threadIdx.x;

  if (bid < 128) {
    for (int i = tid; i < HH * (DD / 4); i += NT) {
      int r = i >> 5, q = i & 31;
      *(float4*)&s_W1[r][q * 4] = *(const float4*)(W1 + (size_t)r * (DD + HH) + q * 4);
    }
    __syncthreads();
    const int jg = tid & 15, ng = tid >> 4;
    const int j0 = jg * 4;
    const size_t n0 = (size_t)bid * 256 + ng * 4;
    const float4* x4 = (const float4*)x;
    float acc[4][4];
#pragma unroll
    for (int i = 0; i < 4; i++)
#pragma unroll
      for (int q = 0; q < 4; q++) acc[i][q] = 0.f;
    for (int kq = 0; kq < 32; kq++) {
      float4 xv[4], wv[4];
#pragma unroll
      for (int i = 0; i < 4; i++) xv[i] = x4[(n0 + i) * 32 + kq];
#pragma unroll
      for (int q = 0; q < 4; q++) wv[q] = *(const float4*)&s_W1[j0 + q][kq * 4];
#pragma unroll
      for (int i = 0; i < 4; i++)
#pragma unroll
        for (int q = 0; q < 4; q++)
          acc[i][q] += xv[i].x * wv[q].x + xv[i].y * wv[q].y +
                       xv[i].z * wv[q].z + xv[i].w * wv[q].w;
    }
#pragma unroll
    for (int i = 0; i < 4; i++)
#pragma unroll
      for (int q = 0; q < 4; q++)
        P[(n0 + i) * HH + j0 + q] = acc[i][q];
  } else if (bid < 384) {
    const int bm = bid - 128;
    const int b = bm >> 4, chunk = bm & 15;
    const int d = tid & (DD - 1), part = tid >> 7;
    float acc = 0.f;
    const int base = chunk * 128 + part;
#pragma unroll
    for (int k = 0; k < 16; k++)
      acc += x[((size_t)b * NB + base + k * 8) * DD + d];
    sp[part][d] = acc;
    __syncthreads();
    if (tid < DD) {
      float m = 0.f;
#pragma unroll
      for (int p = 0; p < 8; p++) m += sp[p][tid];
      partial[((size_t)b * 16 + chunk) * DD + tid] = m;
    }
  } else {
    const int bg = bid - 384;
    const int base = (bg * NT + tid) * 4;
#pragma unroll
    for (int i = 0; i < 4; i++) {
      int idx = base + i;
      int sel = idx >> 15;
      int rem = idx & 32767;
      int c = sel / 3, s = sel - 3 * c;
      unsigned data = (s == 0) ? (unsigned)(2 * c) : (unsigned)(2 * c + 1000 + (s - 1));
      unsigned k0, k1;
      tf2x32(0u, 42u, 0u, data, k0, k1);
      gumb[idx] = gumbel_for(k0, k1, (unsigned)rem);
    }
  }
}

// ---------------- Main: one block (1024 thr) per batch ----------------
__global__ __launch_bounds__(NT, 4) __attribute__((amdgpu_waves_per_eu(4, 4)))
void gvp_main(
    const float* __restrict__ x, const float* __restrict__ adj, const int* __restrict__ mask,
    const float* __restrict__ W1, const float* __restrict__ b1,
    const float* __restrict__ W2, const float* __restrict__ b2,
    const float* __restrict__ Wc, const float* __restrict__ bc,
    const float* __restrict__ Wih, const float* __restrict__ Whh,
    const float* __restrict__ bih, const float* __restrict__ bhh,
    const float* __restrict__ P, const float* __restrict__ partial,
    const float* __restrict__ gumb,
    float* __restrict__ out_feat, float* __restrict__ out_adjm, float* __restrict__ out_assign) {
  const int b = blockIdx.x;
  const int tid = threadIdx.x;

  __shared__ __align__(16) float s_logits[NB];
  __shared__ __align__(16) float s_gumb[2][NB];
  __shared__ unsigned char s_avail[NB], s_reach[NB], s_assignB[NB];
  __shared__ short s_list[128];
  __shared__ int s_cnt;
  __shared__ unsigned long long s_key[CSMAX];
  __shared__ __align__(16) float s_ctx[HH], s_q[HH];
  __shared__ __align__(16) float s_h[2][HH];
  __shared__ __align__(16) float s_hist[MAXC][DD];
  __shared__ __align__(16) float s_giAll[MAXC][3 * HH];
  __shared__ __align__(16) float s_Whh[3 * HH][HH + 4];
  __shared__ __align__(16) float s_W1c[HH][HH + 4];
  __shared__ __align__(16) float s_W2[HH];
  __shared__ float s_bhh[3 * HH], s_b1[HH];
  __shared__ __align__(16) float s_mean[DD];
  __shared__ float s_b2v;

  const size_t xb = (size_t)b * NB * DD;
  const float4* adj4 = (const float4*)(adj + (size_t)b * NB * NB);
  const float4* P4 = (const float4*)(P + (size_t)b * NB * HH);
  const int n0 = tid, n1 = tid + NT;

  auto scanReduce = [&](float bv, int bi, int slot) {
#pragma unroll
    for (int off = 32; off; off >>= 1) {
      float ov = __shfl_down(bv, off);
      int oi = __shfl_down(bi, off);
      if (ov > bv || (ov == bv && oi < bi)) { bv = ov; bi = oi; }
    }
    if ((tid & 63) == 0 && bi < NB) {
      unsigned u = __float_as_uint(bv);
      u = (u & 0x80000000u) ? ~u : (u | 0x80000000u);
      unsigned long long key = ((unsigned long long)u << 32) | (unsigned)(~bi);
      atomicMax(&s_key[slot], key);
    }
  };
  auto decodeIdx = [](unsigned long long k) -> int {
    return k ? (int)(unsigned)(~(unsigned)k) : -1;
  };

  // ---- persistent named registers: P rows (n0, n1) + Wih slice. Loaded ONCE. ----
#define DECLP(i) float4 pA##i, pB##i;
  REP16(DECLP)
#define DECLW(i) float4 wv##i;
  REP8(DECLW)
  {
    const float4* p0r = P4 + (size_t)n0 * 16;
    const float4* p1r = P4 + (size_t)n1 * 16;
#define LOADP(i) pA##i = p0r[i]; pB##i = p1r[i];
    REP16(LOADP)
  }
  if (tid < 4 * 3 * HH) {  // Wih row slice: row = tid>>2, quarter g = tid&3
    const float4* wr = (const float4*)Wih + ((size_t)(tid >> 2) * 32 + (tid & 3) * 8);
#define LOADW(i) wv##i = wr[i];
    REP8(LOADW)
  }
  // cluster-0 gumbel prefetch (floats across staging barriers)
  float4 gst;
  float g0a, g0b;
  {
    const float* g0p = gumb + ((size_t)0 * BB + b) * NB;
    g0a = g0p[n0]; g0b = g0p[n1];
    const float4* g12 = (const float4*)(gumb + ((size_t)(1 + (tid >> 9)) * BB + b) * NB);
    gst = g12[tid & 511];
  }

  // ---- one-time LDS staging ----
  for (int i = tid; i < 3 * HH * (HH / 4); i += NT) {
    int r = i >> 4, q = i & 15;
    *(float4*)&s_Whh[r][q * 4] = *(const float4*)(Whh + (size_t)r * HH + q * 4);
  }
  {
    int r = tid >> 4, q = tid & 15;
    *(float4*)&s_W1c[r][q * 4] = *(const float4*)(W1 + (size_t)r * (DD + HH) + DD + q * 4);
  }
  if (tid < 3 * HH) s_bhh[tid] = bhh[tid];
  if (tid < HH) { s_W2[tid] = W2[tid]; s_b1[tid] = b1[tid]; s_h[0][tid] = 0.f; }
  if (tid == 0) s_b2v = b2[0];
#pragma unroll
  for (int r = 0; r < 2; r++) {
    int n = tid + r * NT;
    s_avail[n] = (mask[b * NB + n] != 0) ? 1 : 0;
    s_assignB[n] = 0;
  }
  if (tid < DD) {
    float m = 0.f;
#pragma unroll
    for (int k = 0; k < 16; k++) m += partial[((size_t)b * 16 + k) * DD + tid];
    s_mean[tid] = m * (1.0f / NB);
  }
  phase_barrier();
  if (tid < 4 * HH) {  // ctx = bc + Wc @ mean
    int row = tid >> 2, g = tid & 3;
    const float4* wr = (const float4*)(Wc + (size_t)row * DD) + g * 8;
    const float4* m4 = (const float4*)s_mean + g * 8;
    float s = 0.f;
#pragma unroll
    for (int i = 0; i < 8; i++) {
      float4 w = wr[i], m = m4[i];
      s += w.x * m.x + w.y * m.y + w.z * m.z + w.w * m.w;
    }
    s += __shfl_xor(s, 1);
    s += __shfl_xor(s, 2);
    if (g == 0) s_ctx[row] = s + bc[row];
  }
  phase_barrier();

  int hp = 0;  // GRU h parity (uniform)

  auto gruStep = [&](int t, int lo, int c) {
    int tt = tid - lo;
    if ((unsigned)tt < 256u) {
      int row = tt >> 2, g = tt & 3;
      const float4* h4 = (const float4*)s_h[hp] + g * 4;
      float4 hv[4];
#pragma unroll
      for (int i = 0; i < 4; i++) hv[i] = h4[i];
      const float4* wr = (const float4*)&s_Whh[row][0] + g * 4;
      const float4* wz = (const float4*)&s_Whh[HH + row][0] + g * 4;
      const float4* wn = (const float4*)&s_Whh[2 * HH + row][0] + g * 4;
      float sr = 0.f, sz = 0.f, sn = 0.f;
#pragma unroll
      for (int i = 0; i < 4; i++) {
        float4 a = wr[i], bz = wz[i], cn = wn[i], h = hv[i];
        sr += a.x * h.x + a.y * h.y + a.z * h.z + a.w * h.w;
        sz += bz.x * h.x + bz.y * h.y + bz.z * h.z + bz.w * h.w;
        sn += cn.x * h.x + cn.y * h.y + cn.z * h.z + cn.w * h.w;
      }
      sr += __shfl_xor(sr, 1); sr += __shfl_xor(sr, 2);
      sz += __shfl_xor(sz, 1); sz += __shfl_xor(sz, 2);
      sn += __shfl_xor(sn, 1); sn += __shfl_xor(sn, 2);
      if (g == 0) {
        float r = 1.f / (1.f + expf(-(s_giAll[t][row] + sr + s_bhh[row])));
        float z = 1.f / (1.f + expf(-(s_giAll[t][HH + row] + sz + s_bhh[HH + row])));
        float nn = tanhf(s_giAll[t][2 * HH + row] + r * (sn + s_bhh[2 * HH + row]));
        float hn = (1.f - z) * nn + z * s_h[hp][row];
        s_h[hp ^ 1][row] = hn;
        if (t == c) s_ctx[row] = hn;
      }
    }
  };

  for (int c = 0; c < MAXC; c++) {
    // ======== T: commit prefetched gumbel, q matvec, reset ========
    ((float4*)s_gumb)[tid] = gst;
    if (tid < 4 * HH) {  // q = b1 + W1[:,DD:] @ ctx
      int row = tid >> 2, g = tid & 3;
      const float4* wr = (const float4*)&s_W1c[row][0] + g * 4;
      const float4* c4 = (const float4*)s_ctx + g * 4;
      float s = 0.f;
#pragma unroll
      for (int i = 0; i < 4; i++) {
        float4 w = wr[i], cc = c4[i];
        s += w.x * cc.x + w.y * cc.y + w.z * cc.z + w.w * cc.w;
      }
      s += __shfl_xor(s, 1);
      s += __shfl_xor(s, 2);
      if (g == 0) s_q[row] = s + s_b1[row];
    }
    if (tid >= 512 && tid < 512 + CSMAX) s_key[tid - 512] = 0ull;
    if (tid == 768) s_cnt = 0;
    phase_barrier();

    // ======== L: logits from persistent regs (pure VALU) + SEL0 ========
    {
      const float4* q4 = (const float4*)s_q;
      const float4* w4 = (const float4*)s_W2;
      float l0 = s_b2v, l1 = s_b2v;
#define ACC(i) { float4 qv = q4[i], w = w4[i]; \
      l0 += w.x * fmaxf(pA##i.x + qv.x, 0.f) + w.y * fmaxf(pA##i.y + qv.y, 0.f) + \
            w.z * fmaxf(pA##i.z + qv.z, 0.f) + w.w * fmaxf(pA##i.w + qv.w, 0.f); \
      l1 += w.x * fmaxf(pB##i.x + qv.x, 0.f) + w.y * fmaxf(pB##i.y + qv.y, 0.f) + \
            w.z * fmaxf(pB##i.z + qv.z, 0.f) + w.w * fmaxf(pB##i.w + qv.w, 0.f); }
      REP16(ACC)
      s_logits[n0] = l0;
      s_logits[n1] = l1;
      float bv = -FLT_MAX;
      int bi = NB;
      if (s_avail[n0]) { float y = l0 + g0a; if (y > bv) { bv = y; bi = n0; } }
      if (s_avail[n1]) { float y = l1 + g0b; if (y > bv || (y == bv && n1 < bi)) { bv = y; bi = n1; } }
      scanReduce(bv, bi, 0);
    }
    phase_barrier();

    // ======== H0: seed row -> reach + frontier ========
    const int seed = decodeIdx(s_key[0]);
    if (tid < 512) {
      if (seed >= 0) {
        float4 a = adj4[(size_t)seed * 512 + tid];
        int m = tid << 2;
        unsigned f0 = a.x > 0.f, f1 = a.y > 0.f, f2 = a.z > 0.f, f3 = a.w > 0.f;
        unsigned r = f0 | (f1 << 8) | (f2 << 16) | (f3 << 24);
        if ((seed >> 2) == tid) r |= 1u << ((seed & 3) * 8);
        ((unsigned*)s_reach)[tid] = r;
        if (f0 && m != seed)     { int p = atomicAdd(&s_cnt, 1); if (p < 128) s_list[p] = (short)m; }
        if (f1 && m + 1 != seed) { int p = atomicAdd(&s_cnt, 1); if (p < 128) s_list[p] = (short)(m + 1); }
        if (f2 && m + 2 != seed) { int p = atomicAdd(&s_cnt, 1); if (p < 128) s_list[p] = (short)(m + 2); }
        if (f3 && m + 3 != seed) { int p = atomicAdd(&s_cnt, 1); if (p < 128) s_list[p] = (short)(m + 3); }
      } else {
        ((unsigned*)s_reach)[tid] = 0u;
      }
    }
    phase_barrier();

    // ======== H1: OR frontier rows into reach ========
    if (seed >= 0) {
      int cnt = min(s_cnt, 128);
      int m4 = tid & 511, rg = tid >> 9;
      bool a0 = false, a1 = false, a2 = false, a3 = false;
#pragma unroll
      for (int k = 0; k < 20; k++) {
        int li = rg + 2 * k;
        if (li < cnt) {
          int n = s_list[li];
          float4 a = adj4[(size_t)n * 512 + m4];
          a0 |= a.x > 0.f; a1 |= a.y > 0.f; a2 |= a.z > 0.f; a3 |= a.w > 0.f;
        }
      }
      for (int li = rg + 40; li < cnt; li += 2) {
        int n = s_list[li];
        float4 a = adj4[(size_t)n * 512 + m4];
        a0 |= a.x > 0.f; a1 |= a.y > 0.f; a2 |= a.z > 0.f; a3 |= a.w > 0.f;
      }
      int m = m4 << 2;
      if (a0) s_reach[m] = 1;
      if (a1) s_reach[m + 1] = 1;
      if (a2) s_reach[m + 2] = 1;
      if (a3) s_reach[m + 3] = 1;
    }
    phase_barrier();

    // ======== S1 ========
    {
      float bv = -FLT_MAX;
      int bi = NB;
#pragma unroll
      for (int r = 0; r < 2; r++) {
        int n = tid + r * NT;
        if (s_avail[n] && s_reach[n] && n != seed) {
          float y = s_logits[n] + s_gumb[0][n];
          if (y > bv || (y == bv && n < bi)) { bv = y; bi = n; }
        }
      }
      scanReduce(bv, bi, 1);
    }
    phase_barrier();

    // ======== S2 ========
    const int w1i = decodeIdx(s_key[1]);
    {
      float bv = -FLT_MAX;
      int bi = NB;
#pragma unroll
      for (int r = 0; r < 2; r++) {
        int n = tid + r * NT;
        if (s_avail[n] && s_reach[n] && n != seed && n != w1i) {
          float y = s_logits[n] + s_gumb[1][n];
          if (y > bv || (y == bv && n < bi)) { bv = y; bi = n; }
        }
      }
      scanReduce(bv, bi, 2);
    }
    phase_barrier();

    // ======== E: prefetch(c+1) gumbel + emb || GRU-step0 (c>=1) || avail update ========
    const int w2i = decodeIdx(s_key[2]);
    if (c + 1 < MAXC) {  // loads float across following barriers (raw s_barrier)
      const float* g0p = gumb + ((size_t)((c + 1) * 3) * BB + b) * NB;
      g0a = g0p[n0]; g0b = g0p[n1];
      const float4* g12 =
          (const float4*)(gumb + ((size_t)((c + 1) * 3 + 1 + (tid >> 9)) * BB + b) * NB);
      gst = g12[tid & 511];
    }
    {
      int mc = (seed >= 0) + (w1i >= 0) + (w2i >= 0);
      if (tid < DD) {
        float acc = 0.f;
        if (seed >= 0) acc += x[xb + (size_t)seed * DD + tid];
        if (w1i >= 0) acc += x[xb + (size_t)w1i * DD + tid];
        if (w2i >= 0) acc += x[xb + (size_t)w2i * DD + tid];
        float e = acc / fmaxf((float)mc, 1.0f);
        s_hist[c][tid] = e;
        out_feat[((size_t)b * MAXC + c) * DD + tid] = e;
      } else if (tid >= 512 && tid < 512 + CSMAX) {
        int idx = (tid == 512) ? seed : (tid == 513 ? w1i : w2i);
        if (idx >= 0) { s_avail[idx] = 0; s_assignB[idx] |= (unsigned char)(1 << c); }
      }
      if (c >= 1) gruStep(0, 256, c);
    }
    phase_barrier();
    if (c >= 1) hp ^= 1;

    // ======== G: gi[c] from persistent Wih regs (tid<768) || GRU-step1 (c>=2) ========
    if (tid < 4 * 3 * HH) {
      int g = tid & 3;
      const float4* h4 = (const float4*)s_hist[c] + g * 8;
      float s = 0.f;
#define GACC(i) { float4 hh = h4[i]; s += wv##i.x * hh.x + wv##i.y * hh.y + \
                  wv##i.z * hh.z + wv##i.w * hh.w; }
      REP8(GACC)
      s += __shfl_xor(s, 1);
      s += __shfl_xor(s, 2);
      if (g == 0) s_giAll[c][tid >> 2] = s + bih[tid >> 2];
    }
    if (c >= 2) gruStep(1, 768, c);
    phase_barrier();
    if (c >= 2) hp ^= 1;

    // ======== R: remaining GRU steps ========
    int t0 = (c == 0) ? 0 : (c == 1) ? 1 : 2;
    for (int t = t0; t <= c; t++) {
      gruStep(t, 0, c);
      hp ^= 1;
      phase_barrier();
    }
  }  // clusters

  // ======== final coalesced assign + cluster_adj ========
#pragma unroll
  for (int r = 0; r < 2; r++) {
    int n = tid + r * NT;
    unsigned bits = s_assignB[n];
    size_t base = ((size_t)(b * NB + n)) * MAXC;
#pragma unroll
    for (int cc = 0; cc < MAXC; cc++)
      out_assign[base + cc] = (float)((bits >> cc) & 1u);
  }
  for (int i = tid; i < MAXC * MAXC; i += NT)
    out_adjm[(size_t)b * MAXC * MAXC + i] = ((i / MAXC) == (i % MAXC)) ? 0.f : 1.f;
}

extern "C" void kernel_launch(void* const* d_in, const int* in_sizes, int n_in,
                              void* d_out, int out_size, void* d_ws, size_t ws_size,
                              hipStream_t stream) {
  const float* x   = (const float*)d_in[0];
  const float* adj = (const float*)d_in[1];
  const int*   mask= (const int*)d_in[2];
  const float* W1  = (const float*)d_in[3];
  const float* b1  = (const float*)d_in[4];
  const float* W2  = (const float*)d_in[5];
  const float* b2  = (const float*)d_in[6];
  const float* Wc  = (const float*)d_in[7];
  const float* bc  = (const float*)d_in[8];
  const float* Wih = (const float*)d_in[9];
  const float* Whh = (const float*)d_in[10];
  const float* bih = (const float*)d_in[11];
  const float* bhh = (const float*)d_in[12];

  float* ws = (float*)d_ws;
  float* P       = ws;                                   // [B*N*HH]  8 MB
  float* partial = P + (size_t)BB * NB * HH;             // [B][16][DD]
  float* gumb    = partial + (size_t)BB * 16 * DD;       // [15][B][N]

  float* out = (float*)d_out;
  float* out_feat = out;                                     // [B,5,D]
  float* out_adjm = out + (size_t)BB * MAXC * DD;            // [B,5,5]
  float* out_assign = out_adjm + (size_t)BB * MAXC * MAXC;   // [B,N,5]

  hipLaunchKernelGGL(gvp_prep, dim3(504), dim3(NT), 0, stream, x, W1, P, partial, gumb);
  hipLaunchKernelGGL(gvp_main, dim3(BB), dim3(NT), 0, stream,
                     x, adj, mask, W1, b1, W2, b2, Wc, bc, Wih, Whh, bih, bhh, P, partial, gumb,
                     out_feat, out_adjm, out_assign);
}